// Round 1
// baseline (163.071 us; speedup 1.0000x reference)
//
#include <hip/hip_runtime.h>
#include <hip/hip_bf16.h>
#include <stdint.h>

// VSN: B=16,T=256 -> NTOK=4096 tokens, V=64 vars, H=256 hidden.
#define NTOK 4096
#define NV 64
#define NH 256
#define LN_EPS 1e-5f

typedef __attribute__((ext_vector_type(8))) short short8;
typedef __attribute__((ext_vector_type(4))) float f32x4;

__device__ __forceinline__ unsigned short f32_to_bf16(float f) {
    uint32_t u = __builtin_bit_cast(uint32_t, f);
    return (unsigned short)((u + 0x7FFFu + ((u >> 16) & 1u)) >> 16);  // RNE
}
__device__ __forceinline__ float fsigmoid(float z) { return 1.0f / (1.0f + __expf(-z)); }
__device__ __forceinline__ float felu(float z) { return z > 0.0f ? z : (__expf(z) - 1.0f); }

// ---------------- Kernel A: W2 [v][h][o] f32 -> W2T [v][o][h] bf16 ----------------
__global__ __launch_bounds__(256) void k_w2t(const float* __restrict__ W2,
                                             unsigned short* __restrict__ W2T) {
    __shared__ float tile[32][33];
    const int v  = blockIdx.x >> 6;
    const int t  = blockIdx.x & 63;
    const int h0 = (t & 7) * 32;
    const int o0 = (t >> 3) * 32;
    const int r  = threadIdx.x >> 3;
    const int c4 = (threadIdx.x & 7) * 4;
    const float4 d = *(const float4*)(W2 + ((size_t)v * NH + h0 + r) * NH + o0 + c4);
    tile[r][c4 + 0] = d.x; tile[r][c4 + 1] = d.y;
    tile[r][c4 + 2] = d.z; tile[r][c4 + 3] = d.w;
    __syncthreads();
    ushort4 o;
    o.x = f32_to_bf16(tile[c4 + 0][r]);
    o.y = f32_to_bf16(tile[c4 + 1][r]);
    o.z = f32_to_bf16(tile[c4 + 2][r]);
    o.w = f32_to_bf16(tile[c4 + 3][r]);
    *(ushort4*)(W2T + ((size_t)v * NH + o0 + r) * NH + h0 + c4) = o;
}

// ---------------- Kernel B: weight-network GRN + softmax -> weights[tok][v] -------
// One wave per token; lane = variable index. All f32.
__global__ __launch_bounds__(256) void k_weights(
    const float* __restrict__ x,
    const float* __restrict__ nW1, const float* __restrict__ nb1,
    const float* __restrict__ nW2, const float* __restrict__ nb2,
    const float* __restrict__ nWg, const float* __restrict__ nbg,
    const float* __restrict__ ng,  const float* __restrict__ nbe,
    float* __restrict__ wout_buf) {
    const int wv = threadIdx.x >> 6;
    const int lane = threadIdx.x & 63;
    const int tok = blockIdx.x * 4 + wv;
    const float xv = x[(size_t)tok * NV + lane];
    float acc1 = nb1[lane], accg = nbg[lane];
#pragma unroll 8
    for (int k = 0; k < 64; ++k) {
        const float xk = __shfl(xv, k);
        acc1 = fmaf(xk, nW1[k * 64 + lane], acc1);
        accg = fmaf(xk, nWg[k * 64 + lane], accg);
    }
    const float h  = felu(acc1);
    const float wg = fsigmoid(accg);
    float acc2 = nb2[lane];
#pragma unroll 8
    for (int k = 0; k < 64; ++k) {
        const float hk = __shfl(h, k);
        acc2 = fmaf(hk, nW2[k * 64 + lane], acc2);
    }
    const float pre = xv + wg * acc2;
    float s = pre;
#pragma unroll
    for (int m = 32; m >= 1; m >>= 1) s += __shfl_xor(s, m);
    const float mu = s * (1.0f / 64.0f);
    const float dd = pre - mu;
    float s2 = dd * dd;
#pragma unroll
    for (int m = 32; m >= 1; m >>= 1) s2 += __shfl_xor(s2, m);
    const float inv = rsqrtf(s2 * (1.0f / 64.0f) + LN_EPS);
    const float wln = dd * inv * ng[lane] + nbe[lane];
    float mx = wln;
#pragma unroll
    for (int m = 32; m >= 1; m >>= 1) mx = fmaxf(mx, __shfl_xor(mx, m));
    const float e = __expf(wln - mx);
    float se = e;
#pragma unroll
    for (int m = 32; m >= 1; m >>= 1) se += __shfl_xor(se, m);
    wout_buf[(size_t)tok * NV + lane] = e / se;
}

// ---------------- Kernel C: fused per-var GRN (MFMA) + weighted accumulate --------
// grid (32 token-tiles, 8 var-groups); 512 thr = 8 waves; wave = 16 tokens x 256 H.
// Per var: A[m][k]=elu(x*W1+b1) generated in regs; B = W2T panel staged in LDS
// (swizzled); 8 K-steps x 16 MFMA(16x16x32 bf16); epilogue gate/skip/LN; weighted
// sum over the group's 8 vars kept in registers (wacc).
__global__ __launch_bounds__(512, 2) void k_main(
    const float* __restrict__ x, const unsigned short* __restrict__ W2T,
    const float* __restrict__ W1, const float* __restrict__ b1,
    const float* __restrict__ Wg, const float* __restrict__ bg,
    const float* __restrict__ Ws, const float* __restrict__ bs,
    const float* __restrict__ b2, const float* __restrict__ g1,
    const float* __restrict__ be1, const float* __restrict__ wgts,
    float* __restrict__ partials,   // [8][NTOK][NH] (preferred) or nullptr
    float* __restrict__ outacc) {   // atomic fallback target
    __shared__ uint4 sB4[1024];     // 16KB B panel, 16B chunks, slot-swizzled
    __shared__ float sRows[9][NH];  // 0:W1 1:b1 2:Wg 3:bg 4:Ws 5:bs 6:b2 7:g1 8:be1
    __shared__ float sX[128][8];
    __shared__ float sW[128][8];

    const int tid  = threadIdx.x;
    const int wv   = tid >> 6;
    const int lane = tid & 63;
    const int c    = lane & 15;   // MFMA col (D) / A-row
    const int kg   = lane >> 4;   // k-group
    const int t0   = blockIdx.x * 128;
    const int vg   = blockIdx.y;
    const int vbase = vg * 8;

    for (int e = tid; e < 1024; e += 512) {
        const int row = e >> 3, cc = e & 7;
        sX[row][cc] = x[(size_t)(t0 + row) * NV + vbase + cc];
        sW[row][cc] = wgts[(size_t)(t0 + row) * NV + vbase + cc];
    }

    const int idx  = tid & 255;
    const int half = tid >> 8;
    // b128 read base: row o = f*16+c, slot rotated by (o>>1) => conflict-free per 8 lanes
    const int rdbase = c * 64 + (((kg + (c >> 1)) & 3) << 4);
    const f32x4 fzero = {0.f, 0.f, 0.f, 0.f};

    f32x4 wacc[16];
#pragma unroll
    for (int f = 0; f < 16; ++f) wacc[f] = fzero;

    for (int vi = 0; vi < 8; ++vi) {
        const int v = vbase + vi;
        __syncthreads();  // prev var fully consumed; sX/sW visible (first iter)
        const size_t vro = (size_t)v * NH;
        if (half == 0) {
            sRows[0][idx] = W1[vro + idx];
            sRows[2][idx] = Wg[vro + idx];
            sRows[4][idx] = Ws[vro + idx];
            sRows[6][idx] = b2[vro + idx];
            sRows[8][idx] = be1[vro + idx];
        } else {
            sRows[1][idx] = b1[vro + idx];
            sRows[3][idx] = bg[vro + idx];
            sRows[5][idx] = bs[vro + idx];
            sRows[7][idx] = g1[vro + idx];
        }
        const float xv = sX[wv * 16 + c][vi];
        const unsigned short* W2Tv = W2T + (size_t)v * NH * NH;

        f32x4 acc[16];
#pragma unroll
        for (int f = 0; f < 16; ++f) acc[f] = fzero;

        for (int ks = 0; ks < 8; ++ks) {
            __syncthreads();
            for (int ch = tid; ch < 1024; ch += 512) {
                const int o = ch >> 2, s = ch & 3;
                const uint4 d = *(const uint4*)(W2Tv + (size_t)o * NH + ks * 32 + s * 8);
                const int slot = (s + (o >> 1)) & 3;
                sB4[(o << 2) | slot] = d;
            }
            __syncthreads();
            const int k0 = ks * 32 + kg * 8;
            uint32_t ap[4];
#pragma unroll
            for (int j = 0; j < 4; ++j) {
                const float z0 = fmaf(xv, sRows[0][k0 + 2 * j],     sRows[1][k0 + 2 * j]);
                const float z1 = fmaf(xv, sRows[0][k0 + 2 * j + 1], sRows[1][k0 + 2 * j + 1]);
                ap[j] = (uint32_t)f32_to_bf16(felu(z0)) |
                        ((uint32_t)f32_to_bf16(felu(z1)) << 16);
            }
            const short8 af = __builtin_bit_cast(short8, ap);
#pragma unroll
            for (int f = 0; f < 16; ++f) {
                const uint4 braw = *(const uint4*)((const char*)sB4 + rdbase + (f << 10));
                const short8 bf = __builtin_bit_cast(short8, braw);
                acc[f] = __builtin_amdgcn_mfma_f32_16x16x32_bf16(af, bf, acc[f], 0, 0, 0);
            }
        }
        // epilogue: lane holds res[tok=t0+wv*16+kg*4+r][h=f*16+c] in acc[f][r]
        const int tl = wv * 16 + kg * 4;
        const float xr0 = sX[tl + 0][vi], xr1 = sX[tl + 1][vi];
        const float xr2 = sX[tl + 2][vi], xr3 = sX[tl + 3][vi];
        float ps0 = 0, ps1 = 0, ps2 = 0, ps3 = 0;
        float pq0 = 0, pq1 = 0, pq2 = 0, pq3 = 0;
#pragma unroll
        for (int f = 0; f < 16; ++f) {
            const int hh = (f << 4) + c;
            const float Wg_ = sRows[2][hh], bg_ = sRows[3][hh];
            const float Ws_ = sRows[4][hh], bs_ = sRows[5][hh], b2_ = sRows[6][hh];
            { const float y = fmaf(xr0, Ws_, bs_) + fsigmoid(fmaf(xr0, Wg_, bg_)) * (acc[f][0] + b2_);
              acc[f][0] = y; ps0 += y; pq0 = fmaf(y, y, pq0); }
            { const float y = fmaf(xr1, Ws_, bs_) + fsigmoid(fmaf(xr1, Wg_, bg_)) * (acc[f][1] + b2_);
              acc[f][1] = y; ps1 += y; pq1 = fmaf(y, y, pq1); }
            { const float y = fmaf(xr2, Ws_, bs_) + fsigmoid(fmaf(xr2, Wg_, bg_)) * (acc[f][2] + b2_);
              acc[f][2] = y; ps2 += y; pq2 = fmaf(y, y, pq2); }
            { const float y = fmaf(xr3, Ws_, bs_) + fsigmoid(fmaf(xr3, Wg_, bg_)) * (acc[f][3] + b2_);
              acc[f][3] = y; ps3 += y; pq3 = fmaf(y, y, pq3); }
        }
#pragma unroll
        for (int mask = 1; mask <= 8; mask <<= 1) {  // LN reduce within 16-lane group
            ps0 += __shfl_xor(ps0, mask); ps1 += __shfl_xor(ps1, mask);
            ps2 += __shfl_xor(ps2, mask); ps3 += __shfl_xor(ps3, mask);
            pq0 += __shfl_xor(pq0, mask); pq1 += __shfl_xor(pq1, mask);
            pq2 += __shfl_xor(pq2, mask); pq3 += __shfl_xor(pq3, mask);
        }
        const float mu0 = ps0 * (1.0f / 256.0f), mu1 = ps1 * (1.0f / 256.0f);
        const float mu2 = ps2 * (1.0f / 256.0f), mu3 = ps3 * (1.0f / 256.0f);
        const float iv0 = rsqrtf(fmaf(-mu0, mu0, pq0 * (1.0f / 256.0f)) + LN_EPS);
        const float iv1 = rsqrtf(fmaf(-mu1, mu1, pq1 * (1.0f / 256.0f)) + LN_EPS);
        const float iv2 = rsqrtf(fmaf(-mu2, mu2, pq2 * (1.0f / 256.0f)) + LN_EPS);
        const float iv3 = rsqrtf(fmaf(-mu3, mu3, pq3 * (1.0f / 256.0f)) + LN_EPS);
        const float w0 = sW[tl + 0][vi], w1 = sW[tl + 1][vi];
        const float w2 = sW[tl + 2][vi], w3 = sW[tl + 3][vi];
#pragma unroll
        for (int f = 0; f < 16; ++f) {
            const int hh = (f << 4) + c;
            const float g1_ = sRows[7][hh], be_ = sRows[8][hh];
            wacc[f][0] = fmaf(w0, fmaf((acc[f][0] - mu0) * iv0, g1_, be_), wacc[f][0]);
            wacc[f][1] = fmaf(w1, fmaf((acc[f][1] - mu1) * iv1, g1_, be_), wacc[f][1]);
            wacc[f][2] = fmaf(w2, fmaf((acc[f][2] - mu2) * iv2, g1_, be_), wacc[f][2]);
            wacc[f][3] = fmaf(w3, fmaf((acc[f][3] - mu3) * iv3, g1_, be_), wacc[f][3]);
        }
    }

    const int tokb = t0 + wv * 16 + kg * 4;
    if (partials) {
        float* P = partials + (size_t)vg * NTOK * NH;
#pragma unroll
        for (int f = 0; f < 16; ++f) {
            const int hh = (f << 4) + c;
            P[(size_t)(tokb + 0) * NH + hh] = wacc[f][0];
            P[(size_t)(tokb + 1) * NH + hh] = wacc[f][1];
            P[(size_t)(tokb + 2) * NH + hh] = wacc[f][2];
            P[(size_t)(tokb + 3) * NH + hh] = wacc[f][3];
        }
    } else {
#pragma unroll
        for (int f = 0; f < 16; ++f) {
            const int hh = (f << 4) + c;
            atomicAdd(&outacc[(size_t)(tokb + 0) * NH + hh], wacc[f][0]);
            atomicAdd(&outacc[(size_t)(tokb + 1) * NH + hh], wacc[f][1]);
            atomicAdd(&outacc[(size_t)(tokb + 2) * NH + hh], wacc[f][2]);
            atomicAdd(&outacc[(size_t)(tokb + 3) * NH + hh], wacc[f][3]);
        }
    }
}

// ---------------- Kernel D: sum the 8 vgroup partials ----------------
__global__ __launch_bounds__(256) void k_reduce(const float* __restrict__ P,
                                                float* __restrict__ out) {
    const size_t i = ((size_t)blockIdx.x * 256 + threadIdx.x);
    const f32x4* P4 = (const f32x4*)P;
    f32x4 s = P4[i];
#pragma unroll
    for (int sl = 1; sl < 8; ++sl) s += P4[(size_t)sl * (NTOK * NH / 4) + i];
    ((f32x4*)out)[i] = s;
}

extern "C" void kernel_launch(void* const* d_in, const int* in_sizes, int n_in,
                              void* d_out, int out_size, void* d_ws, size_t ws_size,
                              hipStream_t stream) {
    const float* x   = (const float*)d_in[0];
    const float* W1  = (const float*)d_in[1];
    const float* b1  = (const float*)d_in[2];
    const float* W2  = (const float*)d_in[3];
    const float* b2  = (const float*)d_in[4];
    const float* Wg  = (const float*)d_in[5];
    const float* bg  = (const float*)d_in[6];
    const float* Ws  = (const float*)d_in[7];
    const float* bs  = (const float*)d_in[8];
    const float* g1  = (const float*)d_in[9];
    const float* be1 = (const float*)d_in[10];
    const float* nW1 = (const float*)d_in[11];
    const float* nb1 = (const float*)d_in[12];
    const float* nW2 = (const float*)d_in[13];
    const float* nb2 = (const float*)d_in[14];
    const float* nWg = (const float*)d_in[15];
    const float* nbg = (const float*)d_in[16];
    const float* ng  = (const float*)d_in[17];
    const float* nbe = (const float*)d_in[18];
    float* out = (float*)d_out;

    // ws layout: [0,1MB) weights | [1MB,9MB) W2T bf16 | [9MB,41MB) partials
    char* ws = (char*)d_ws;
    float* ws_wgt = (float*)ws;
    unsigned short* ws_W2T = (unsigned short*)(ws + (1 << 20));
    const size_t part_off = (size_t)9 << 20;
    const size_t part_bytes = (size_t)8 * NTOK * NH * 4;
    const bool use_part = ws_size >= part_off + part_bytes;  // needs >=9MB regardless
    float* ws_part = use_part ? (float*)(ws + part_off) : nullptr;

    k_w2t<<<dim3(64 * 64), dim3(256), 0, stream>>>(W2, ws_W2T);
    k_weights<<<dim3(NTOK / 4), dim3(256), 0, stream>>>(x, nW1, nb1, nW2, nb2,
                                                        nWg, nbg, ng, nbe, ws_wgt);
    if (!use_part) hipMemsetAsync(d_out, 0, (size_t)out_size * 4, stream);
    k_main<<<dim3(32, 8), dim3(512), 0, stream>>>(x, ws_W2T, W1, b1, Wg, bg, Ws, bs,
                                                  b2, g1, be1, ws_wgt, ws_part, out);
    if (use_part)
        k_reduce<<<dim3(NTOK * NH / 4 / 256), dim3(256), 0, stream>>>(ws_part, out);
}

// Round 2
// 141.911 us; speedup vs baseline: 1.1491x; 1.1491x over previous
//
#include <hip/hip_runtime.h>
#include <hip/hip_bf16.h>
#include <stdint.h>

// VSN: B=16,T=256 -> NTOK=4096 tokens, V=64 vars, H=256 hidden.
#define NTOK 4096
#define NV 64
#define NH 256
#define LN_EPS 1e-5f

typedef __attribute__((ext_vector_type(8))) short short8;
typedef __attribute__((ext_vector_type(4))) float f32x4;
typedef __attribute__((ext_vector_type(4))) uint32_t u32x4;

__device__ __forceinline__ unsigned short f32_to_bf16(float f) {
    uint32_t u = __builtin_bit_cast(uint32_t, f);
    return (unsigned short)((u + 0x7FFFu + ((u >> 16) & 1u)) >> 16);  // RNE
}
__device__ __forceinline__ float fsigmoid(float z) { return 1.0f / (1.0f + __expf(-z)); }
__device__ __forceinline__ float felu(float z) { return z > 0.0f ? z : (__expf(z) - 1.0f); }
// pack two f32 -> bf16x2 (round-half-up) in 3 ops: 2 adds + v_perm
__device__ __forceinline__ uint32_t pack_bf16x2(float ze, float zo) {
    const uint32_t ue = __builtin_bit_cast(uint32_t, ze) + 0x8000u;
    const uint32_t uo = __builtin_bit_cast(uint32_t, zo) + 0x8000u;
    return __builtin_amdgcn_perm(uo, ue, 0x07060302u);  // (hi16(uo)<<16)|hi16(ue)
}
__device__ __forceinline__ void gload16(const void* g, void* l) {
    __builtin_amdgcn_global_load_lds(
        (const __attribute__((address_space(1))) uint32_t*)g,
        (__attribute__((address_space(3))) uint32_t*)l, 16, 0, 0);
}

// ---------------- Kernel A: W2 [v][h][o] f32 -> W2T [v][o][h] bf16 ----------------
__global__ __launch_bounds__(256) void k_w2t(const float* __restrict__ W2,
                                             unsigned short* __restrict__ W2T) {
    __shared__ float tile[32][33];
    const int v  = blockIdx.x >> 6;
    const int t  = blockIdx.x & 63;
    const int h0 = (t & 7) * 32;
    const int o0 = (t >> 3) * 32;
    const int r  = threadIdx.x >> 3;
    const int c4 = (threadIdx.x & 7) * 4;
    const float4 d = *(const float4*)(W2 + ((size_t)v * NH + h0 + r) * NH + o0 + c4);
    tile[r][c4 + 0] = d.x; tile[r][c4 + 1] = d.y;
    tile[r][c4 + 2] = d.z; tile[r][c4 + 3] = d.w;
    __syncthreads();
    ushort4 o;
    o.x = f32_to_bf16(tile[c4 + 0][r]);
    o.y = f32_to_bf16(tile[c4 + 1][r]);
    o.z = f32_to_bf16(tile[c4 + 2][r]);
    o.w = f32_to_bf16(tile[c4 + 3][r]);
    *(ushort4*)(W2T + ((size_t)v * NH + o0 + r) * NH + h0 + c4) = o;
}

// ---------------- Kernel B: weight-network GRN + softmax -> weights[tok][v] -------
__global__ __launch_bounds__(256) void k_weights(
    const float* __restrict__ x,
    const float* __restrict__ nW1, const float* __restrict__ nb1,
    const float* __restrict__ nW2, const float* __restrict__ nb2,
    const float* __restrict__ nWg, const float* __restrict__ nbg,
    const float* __restrict__ ng,  const float* __restrict__ nbe,
    float* __restrict__ wout_buf) {
    const int wv = threadIdx.x >> 6;
    const int lane = threadIdx.x & 63;
    const int tok = blockIdx.x * 4 + wv;
    const float xv = x[(size_t)tok * NV + lane];
    float acc1 = nb1[lane], accg = nbg[lane];
#pragma unroll 8
    for (int k = 0; k < 64; ++k) {
        const float xk = __shfl(xv, k);
        acc1 = fmaf(xk, nW1[k * 64 + lane], acc1);
        accg = fmaf(xk, nWg[k * 64 + lane], accg);
    }
    const float h  = felu(acc1);
    const float wg = fsigmoid(accg);
    float acc2 = nb2[lane];
#pragma unroll 8
    for (int k = 0; k < 64; ++k) {
        const float hk = __shfl(h, k);
        acc2 = fmaf(hk, nW2[k * 64 + lane], acc2);
    }
    const float pre = xv + wg * acc2;
    float s = pre;
#pragma unroll
    for (int m = 32; m >= 1; m >>= 1) s += __shfl_xor(s, m);
    const float mu = s * (1.0f / 64.0f);
    const float dd = pre - mu;
    float s2 = dd * dd;
#pragma unroll
    for (int m = 32; m >= 1; m >>= 1) s2 += __shfl_xor(s2, m);
    const float inv = rsqrtf(s2 * (1.0f / 64.0f) + LN_EPS);
    const float wln = dd * inv * ng[lane] + nbe[lane];
    float mx = wln;
#pragma unroll
    for (int m = 32; m >= 1; m >>= 1) mx = fmaxf(mx, __shfl_xor(mx, m));
    const float e = __expf(wln - mx);
    float se = e;
#pragma unroll
    for (int m = 32; m >= 1; m >>= 1) se += __shfl_xor(se, m);
    wout_buf[(size_t)tok * NV + lane] = e / se;
}

// ---------------- Kernel C: fused per-var GRN (MFMA) + weighted accumulate --------
// grid 256 (bid&7 = vgroup -> XCD affinity; bid>>3 = 128-token tile). 512 thr,
// 8 waves = 4 token-groups x 2 H-halves; wave = 32 tok x 128 H (M=32: two 16x16
// A-tiles share each B-frag read -> half the LDS B traffic). B panels + param
// rows staged via global_load_lds (pre-swizzled global source), double-buffered.
__global__ __launch_bounds__(512, 2) void k_main(
    const float* __restrict__ x, const unsigned short* __restrict__ W2T,
    const float* __restrict__ W1, const float* __restrict__ b1,
    const float* __restrict__ Wg, const float* __restrict__ bg,
    const float* __restrict__ Ws, const float* __restrict__ bs,
    const float* __restrict__ b2, const float* __restrict__ g1,
    const float* __restrict__ be1, const float* __restrict__ wgts,
    float* __restrict__ partials,   // [8][NTOK][NH] or nullptr
    float* __restrict__ outacc) {   // atomic fallback
    __shared__ u32x4 sB[2][1024];     // 2 x 16KB B K-step panel, slot-swizzled
    __shared__ float sRB[2][9][256];  // 2 x {W1,b1,Wg,bg,Ws,bs,b2,g1,be1}
    __shared__ float sX[128][9];
    __shared__ float sW[128][9];
    __shared__ float sLN[128][2][2];  // [tok][hh][ps,pq]

    const int tid  = threadIdx.x;
    const int wid  = tid >> 6, lane = tid & 63;
    const int c    = lane & 15, kg = lane >> 4;
    const int tg   = wid >> 1, hh = wid & 1;
    const int bid  = blockIdx.x;
    const int vg   = bid & 7, tt = bid >> 3;
    const int t0   = tt * 128, vbase = vg * 8;

    // ---- prologue: issue stages first, fill sX/sW under them ----
    const unsigned short* W2Tv0 = W2T + (size_t)vbase * (NH * NH);
#pragma unroll
    for (int q = 0; q < 2; ++q) {   // B(v=vbase, ks=0) -> sB[0]
        const int idx = wid * 128 + q * 64 + lane;
        const int o = idx >> 2, sl = idx & 3;
        const int s = (sl - (o >> 1)) & 3;
        gload16(W2Tv0 + (size_t)o * NH + s * 8, (char*)sB[0] + (size_t)(wid * 128 + q * 64) * 16);
    }
    {   // param rows v=vbase -> sRB[0]; wave wid stages row wid (wave0 also row 8)
        const float* rp = wid == 0 ? W1 : wid == 1 ? b1 : wid == 2 ? Wg : wid == 3 ? bg
                        : wid == 4 ? Ws : wid == 5 ? bs : wid == 6 ? b2 : g1;
        gload16(rp + (size_t)vbase * NH + lane * 4, (char*)sRB[0] + wid * 1024);
        if (wid == 0)
            gload16(be1 + (size_t)vbase * NH + lane * 4, (char*)sRB[0] + 8 * 1024);
    }
    for (int e = tid; e < 1024; e += 512) {
        const int row = e >> 3, cc = e & 7;
        sX[row][cc] = x[(size_t)(t0 + row) * NV + vbase + cc];
        sW[row][cc] = wgts[(size_t)(t0 + row) * NV + vbase + cc];
    }
    __syncthreads();

    // b128 B-frag read base: row o = (hh*8+f)*16+c, slot rotated -> balanced banks
    const int rdbase = hh * 8192 + c * 64 + (((kg + (c >> 1)) & 3) << 4);
    const f32x4 fzero = {0.f, 0.f, 0.f, 0.f};

    f32x4 wacc[2][8];
#pragma unroll
    for (int rt = 0; rt < 2; ++rt)
#pragma unroll
        for (int f = 0; f < 8; ++f) wacc[rt][f] = fzero;

    for (int vi = 0; vi < 8; ++vi) {
        const int rcur = vi & 1;
        const unsigned short* W2Tv = W2T + (size_t)(vbase + vi) * (NH * NH);

        f32x4 acc[2][8];
#pragma unroll
        for (int rt = 0; rt < 2; ++rt)
#pragma unroll
            for (int f = 0; f < 8; ++f) acc[rt][f] = fzero;

        for (int ks = 0; ks < 8; ++ks) {
            const int cb = ks & 1;
            // -- prefetch next panel / next var's rows (before compute) --
            if (ks == 0 && vi < 7) {
                const float* rp = wid == 0 ? W1 : wid == 1 ? b1 : wid == 2 ? Wg : wid == 3 ? bg
                                : wid == 4 ? Ws : wid == 5 ? bs : wid == 6 ? b2 : g1;
                gload16(rp + (size_t)(vbase + vi + 1) * NH + lane * 4,
                        (char*)sRB[rcur ^ 1] + wid * 1024);
                if (wid == 0)
                    gload16(be1 + (size_t)(vbase + vi + 1) * NH + lane * 4,
                            (char*)sRB[rcur ^ 1] + 8 * 1024);
            }
            if (ks < 7 || vi < 7) {
                const unsigned short* Wsrc = (ks < 7) ? W2Tv : (W2Tv + NH * NH);
                const int ksn = (ks < 7) ? (ks + 1) : 0;
#pragma unroll
                for (int q = 0; q < 2; ++q) {
                    const int idx = wid * 128 + q * 64 + lane;
                    const int o = idx >> 2, sl = idx & 3;
                    const int s = (sl - (o >> 1)) & 3;
                    gload16(Wsrc + (size_t)o * NH + ksn * 32 + s * 8,
                            (char*)sB[cb ^ 1] + (size_t)(wid * 128 + q * 64) * 16);
                }
            }
            // -- A-frag gen (2 row-tiles) --
            const int k0 = ks * 32 + kg * 8;
            const float4 wA = *(const float4*)&sRB[rcur][0][k0];
            const float4 wB = *(const float4*)&sRB[rcur][0][k0 + 4];
            const float4 bA = *(const float4*)&sRB[rcur][1][k0];
            const float4 bB = *(const float4*)&sRB[rcur][1][k0 + 4];
            const float xv0 = sX[tg * 32 + c][vi];
            const float xv1 = sX[tg * 32 + 16 + c][vi];
            u32x4 ap0, ap1;
            {
                const float z0 = fmaf(xv0, wA.x, bA.x), z1 = fmaf(xv0, wA.y, bA.y);
                const float z2 = fmaf(xv0, wA.z, bA.z), z3 = fmaf(xv0, wA.w, bA.w);
                const float z4 = fmaf(xv0, wB.x, bB.x), z5 = fmaf(xv0, wB.y, bB.y);
                const float z6 = fmaf(xv0, wB.z, bB.z), z7 = fmaf(xv0, wB.w, bB.w);
                ap0[0] = pack_bf16x2(felu(z0), felu(z1));
                ap0[1] = pack_bf16x2(felu(z2), felu(z3));
                ap0[2] = pack_bf16x2(felu(z4), felu(z5));
                ap0[3] = pack_bf16x2(felu(z6), felu(z7));
            }
            {
                const float z0 = fmaf(xv1, wA.x, bA.x), z1 = fmaf(xv1, wA.y, bA.y);
                const float z2 = fmaf(xv1, wA.z, bA.z), z3 = fmaf(xv1, wA.w, bA.w);
                const float z4 = fmaf(xv1, wB.x, bB.x), z5 = fmaf(xv1, wB.y, bB.y);
                const float z6 = fmaf(xv1, wB.z, bB.z), z7 = fmaf(xv1, wB.w, bB.w);
                ap1[0] = pack_bf16x2(felu(z0), felu(z1));
                ap1[1] = pack_bf16x2(felu(z2), felu(z3));
                ap1[2] = pack_bf16x2(felu(z4), felu(z5));
                ap1[3] = pack_bf16x2(felu(z6), felu(z7));
            }
            const short8 af0 = __builtin_bit_cast(short8, ap0);
            const short8 af1 = __builtin_bit_cast(short8, ap1);
            const char* bb = (const char*)sB[cb] + rdbase;
#pragma unroll
            for (int f = 0; f < 8; ++f) {
                const short8 bf = __builtin_bit_cast(short8, *(const u32x4*)(bb + (f << 10)));
                acc[0][f] = __builtin_amdgcn_mfma_f32_16x16x32_bf16(af0, bf, acc[0][f], 0, 0, 0);
                acc[1][f] = __builtin_amdgcn_mfma_f32_16x16x32_bf16(af1, bf, acc[1][f], 0, 0, 0);
            }
            __syncthreads();   // drains prefetch (vmcnt0) + buffer swap
        }

        // -- epilogue: gate/skip/sigmoid, cross-wave LN, weighted accumulate --
        float xr[2][4], wv_[2][4], gv[8], bev[8];
#pragma unroll
        for (int rt = 0; rt < 2; ++rt)
#pragma unroll
            for (int r = 0; r < 4; ++r) {
                const int tl = tg * 32 + rt * 16 + kg * 4 + r;
                xr[rt][r]  = sX[tl][vi];
                wv_[rt][r] = sW[tl][vi];
            }
        float ps[2][4] = {}, pq[2][4] = {};
#pragma unroll
        for (int f = 0; f < 8; ++f) {
            const int h = ((hh << 3) + f) * 16 + c;
            const float Wg_ = sRB[rcur][2][h], bg_ = sRB[rcur][3][h];
            const float Ws_ = sRB[rcur][4][h], bs_ = sRB[rcur][5][h];
            const float b2_ = sRB[rcur][6][h];
            gv[f] = sRB[rcur][7][h]; bev[f] = sRB[rcur][8][h];
#pragma unroll
            for (int rt = 0; rt < 2; ++rt)
#pragma unroll
                for (int r = 0; r < 4; ++r) {
                    const float y = fmaf(xr[rt][r], Ws_, bs_) +
                                    fsigmoid(fmaf(xr[rt][r], Wg_, bg_)) * (acc[rt][f][r] + b2_);
                    acc[rt][f][r] = y;
                    ps[rt][r] += y;
                    pq[rt][r] = fmaf(y, y, pq[rt][r]);
                }
        }
#pragma unroll
        for (int m = 1; m <= 8; m <<= 1)
#pragma unroll
            for (int rt = 0; rt < 2; ++rt)
#pragma unroll
                for (int r = 0; r < 4; ++r) {
                    ps[rt][r] += __shfl_xor(ps[rt][r], m);
                    pq[rt][r] += __shfl_xor(pq[rt][r], m);
                }
        if (c == 0) {
#pragma unroll
            for (int rt = 0; rt < 2; ++rt)
#pragma unroll
                for (int r = 0; r < 4; ++r) {
                    const int tl = tg * 32 + rt * 16 + kg * 4 + r;
                    *(float2*)&sLN[tl][hh][0] = float2{ps[rt][r], pq[rt][r]};
                }
        }
        __syncthreads();  // sLN ready; also fences all sRB[rcur] reads before overwrite
#pragma unroll
        for (int rt = 0; rt < 2; ++rt)
#pragma unroll
            for (int r = 0; r < 4; ++r) {
                const int tl = tg * 32 + rt * 16 + kg * 4 + r;
                const float4 q4 = *(const float4*)&sLN[tl][0][0];
                const float mu = (q4.x + q4.z) * (1.0f / 256.0f);
                const float vr = (q4.y + q4.w) * (1.0f / 256.0f) - mu * mu;
                const float iv = rsqrtf(vr + LN_EPS);
#pragma unroll
                for (int f = 0; f < 8; ++f)
                    wacc[rt][f][r] = fmaf(wv_[rt][r],
                                          fmaf((acc[rt][f][r] - mu) * iv, gv[f], bev[f]),
                                          wacc[rt][f][r]);
            }
    }

    // -- write per-vgroup partials --
    if (partials) {
        float* P = partials + (size_t)vg * NTOK * NH;
#pragma unroll
        for (int rt = 0; rt < 2; ++rt)
#pragma unroll
            for (int r = 0; r < 4; ++r) {
                float* rowp = P + (size_t)(t0 + tg * 32 + rt * 16 + kg * 4 + r) * NH + hh * 128 + c;
#pragma unroll
                for (int f = 0; f < 8; ++f) rowp[f * 16] = wacc[rt][f][r];
            }
    } else {
#pragma unroll
        for (int rt = 0; rt < 2; ++rt)
#pragma unroll
            for (int r = 0; r < 4; ++r) {
                float* rowp = outacc + (size_t)(t0 + tg * 32 + rt * 16 + kg * 4 + r) * NH + hh * 128 + c;
#pragma unroll
                for (int f = 0; f < 8; ++f) atomicAdd(&rowp[f * 16], wacc[rt][f][r]);
            }
    }
}

// ---------------- Kernel D: sum the 8 vgroup partials ----------------
__global__ __launch_bounds__(256) void k_reduce(const float* __restrict__ P,
                                                float* __restrict__ out) {
    const size_t i = ((size_t)blockIdx.x * 256 + threadIdx.x);
    const f32x4* P4 = (const f32x4*)P;
    f32x4 s = P4[i];
#pragma unroll
    for (int sl = 1; sl < 8; ++sl) s += P4[(size_t)sl * (NTOK * NH / 4) + i];
    ((f32x4*)out)[i] = s;
}

extern "C" void kernel_launch(void* const* d_in, const int* in_sizes, int n_in,
                              void* d_out, int out_size, void* d_ws, size_t ws_size,
                              hipStream_t stream) {
    const float* x   = (const float*)d_in[0];
    const float* W1  = (const float*)d_in[1];
    const float* b1  = (const float*)d_in[2];
    const float* W2  = (const float*)d_in[3];
    const float* b2  = (const float*)d_in[4];
    const float* Wg  = (const float*)d_in[5];
    const float* bg  = (const float*)d_in[6];
    const float* Ws  = (const float*)d_in[7];
    const float* bs  = (const float*)d_in[8];
    const float* g1  = (const float*)d_in[9];
    const float* be1 = (const float*)d_in[10];
    const float* nW1 = (const float*)d_in[11];
    const float* nb1 = (const float*)d_in[12];
    const float* nW2 = (const float*)d_in[13];
    const float* nb2 = (const float*)d_in[14];
    const float* nWg = (const float*)d_in[15];
    const float* nbg = (const float*)d_in[16];
    const float* ng  = (const float*)d_in[17];
    const float* nbe = (const float*)d_in[18];
    float* out = (float*)d_out;

    // ws layout: [0,1MB) weights | [1MB,9MB) W2T bf16 | [9MB,41MB) partials
    char* ws = (char*)d_ws;
    float* ws_wgt = (float*)ws;
    unsigned short* ws_W2T = (unsigned short*)(ws + (1 << 20));
    const size_t part_off = (size_t)9 << 20;
    const size_t part_bytes = (size_t)8 * NTOK * NH * 4;
    const bool use_part = ws_size >= part_off + part_bytes;
    float* ws_part = use_part ? (float*)(ws + part_off) : nullptr;

    k_w2t<<<dim3(64 * 64), dim3(256), 0, stream>>>(W2, ws_W2T);
    k_weights<<<dim3(NTOK / 4), dim3(256), 0, stream>>>(x, nW1, nb1, nW2, nb2,
                                                        nWg, nbg, ng, nbe, ws_wgt);
    if (!use_part) hipMemsetAsync(d_out, 0, (size_t)out_size * 4, stream);
    k_main<<<dim3(256), dim3(512), 0, stream>>>(x, ws_W2T, W1, b1, Wg, bg, Ws, bs,
                                                b2, g1, be1, ws_wgt, ws_part, out);
    if (use_part)
        k_reduce<<<dim3(NTOK * NH / 4 / 256), dim3(256), 0, stream>>>(ws_part, out);
}